// Round 7
// baseline (241.154 us; speedup 1.0000x reference)
//
#include <hip/hip_runtime.h>
#include <hip/hip_cooperative_groups.h>
#include <math.h>

namespace cg = cooperative_groups;

#define N_NODES 10000
#define N_EDGES 160000
#define NCHUNK 64                   // edge chunks per scattered quantity
#define EPC (N_EDGES / NCHUNK)      // 2500 edges per chunk
#define GPC (EPC / 4)               // 625 int4-groups per chunk
#define GRID 192

// Single cooperative kernel: 6 stages separated by grid.sync() instead of 6
// dispatches separated by graph-node boundaries. No global atomics anywhere:
// every scatter is LDS-privatized per-block over a 2500-edge chunk, written to
// per-chunk partial arrays, then tree-reduced with coalesced float4 loads.
// All ws arrays are written before read; no zeroing needed.
//
// Workspace layout (floats):
//   [0       .. 10000)    s1   (final)       = scatter(ew * x[src])
//   [10000   .. 20000)    deg  (final)       = scatter(ew)
//   [20000   .. 30000)    t2   (final)       = scatter(ew * s1[src])
//   [30000   .. 40000)    Bf   (final)       = scatter(ew * deg[src])
//   [40000   .. 40512)    p = (W1row@W2)@W3
//   [40512   .. 41024)    q = (b1@W2)@W3
//   [41024   .. 41536)    r = b2@W3
//   [42000   .. 46096)    u_part[16][256]
//   [46096   .. 50192)    v_part[16][256]
//   [50192   .. 58384)    p_part[16][512]
//   [58384   .. 66576)    q_part[16][512]
//   [66576   .. 74768)    r_part[16][512]
//   [80000   .. 720000)   s1_part[64][10000]
//   [720000  .. 1360000)  deg_part[64][10000]
//   [1360000 .. 2000000)  t2_part[64][10000]
//   [2000000 .. 2640000)  B_part[64][10000]
//   [2640000 .. 3280000)  A_part[64][10000]

__device__ __forceinline__ void chunk_scatter(
        const int* __restrict__ src, const int* __restrict__ dst,
        const float* __restrict__ ew, const float* __restrict__ gsrc,
        float* __restrict__ lds, float* __restrict__ part,
        int chunk, int tid) {
    for (int g = tid; g < N_NODES / 4; g += 512)
        ((float4*)lds)[g] = make_float4(0.f, 0.f, 0.f, 0.f);
    __syncthreads();
    int base = chunk * GPC;
    for (int g = tid; g < GPC; g += 512) {
        int4   s4 = ((const int4*)src)[base + g];
        int4   d4 = ((const int4*)dst)[base + g];
        float4 w4 = ((const float4*)ew)[base + g];
        atomicAdd(&lds[d4.x], w4.x * gsrc[s4.x]);
        atomicAdd(&lds[d4.y], w4.y * gsrc[s4.y]);
        atomicAdd(&lds[d4.z], w4.z * gsrc[s4.z]);
        atomicAdd(&lds[d4.w], w4.w * gsrc[s4.w]);
    }
    __syncthreads();
    float* dstp = part + chunk * N_NODES;
    for (int g = tid; g < N_NODES / 4; g += 512)
        ((float4*)dstp)[g] = ((float4*)lds)[g];
}

__device__ __forceinline__ void reduce64_f4(
        const float* __restrict__ part, float* __restrict__ outv, int gid) {
    // gid in [0, 2500): float4 column; sums 64 partial rows
    float4 a = make_float4(0.f, 0.f, 0.f, 0.f);
    #pragma unroll 8
    for (int b = 0; b < NCHUNK; ++b) {
        float4 v = ((const float4*)(part + b * N_NODES))[gid];
        a.x += v.x; a.y += v.y; a.z += v.z; a.w += v.w;
    }
    ((float4*)outv)[gid] = a;
}

__global__ __launch_bounds__(512) void fused_kernel(
        const int* __restrict__ src, const int* __restrict__ dst,
        const float* __restrict__ ew, const float* __restrict__ x,
        const float* __restrict__ W1, const float* __restrict__ b1,
        const float* __restrict__ W2, const float* __restrict__ b2,
        const float* __restrict__ W3, const float* __restrict__ b3,
        float* __restrict__ ws, float* __restrict__ out) {
    cg::grid_group grid = cg::this_grid();
    __shared__ __align__(16) float lds[N_NODES];
    __shared__ float su[16], sv[16], sb[16];
    __shared__ float sA[512];
    __shared__ float A_l[32], B_l[32], D_l[32];

    float* s1       = ws;
    float* deg      = ws + 10000;
    float* t2       = ws + 20000;
    float* Bf       = ws + 30000;
    float* p        = ws + 40000;
    float* q        = ws + 40512;
    float* r        = ws + 41024;
    float* u_part   = ws + 42000;
    float* v_part   = ws + 46096;
    float* p_part   = ws + 50192;
    float* q_part   = ws + 58384;
    float* r_part   = ws + 66576;
    float* s1_part  = ws + 80000;
    float* deg_part = ws + 720000;
    float* t2_part  = ws + 1360000;
    float* B_part   = ws + 2000000;
    float* A_part   = ws + 2640000;

    int tid = threadIdx.x;
    int blk = blockIdx.x;

    // ---- S1: s1_part (blk<64), deg_part (64..127), u/v partials (128..143)
    if (blk < 64) {
        // gsrc = x gathered per src node
        for (int g = tid; g < N_NODES / 4; g += 512)
            ((float4*)lds)[g] = make_float4(0.f, 0.f, 0.f, 0.f);
        __syncthreads();
        int base = blk * GPC;
        for (int g = tid; g < GPC; g += 512) {
            int4   s4 = ((const int4*)src)[base + g];
            int4   d4 = ((const int4*)dst)[base + g];
            float4 w4 = ((const float4*)ew)[base + g];
            atomicAdd(&lds[d4.x], w4.x * x[s4.x]);
            atomicAdd(&lds[d4.y], w4.y * x[s4.y]);
            atomicAdd(&lds[d4.z], w4.z * x[s4.z]);
            atomicAdd(&lds[d4.w], w4.w * x[s4.w]);
        }
        __syncthreads();
        float* dstp = s1_part + blk * N_NODES;
        for (int g = tid; g < N_NODES / 4; g += 512)
            ((float4*)dstp)[g] = ((float4*)lds)[g];
    } else if (blk < 128) {
        int b = blk - 64;
        for (int g = tid; g < N_NODES / 4; g += 512)
            ((float4*)lds)[g] = make_float4(0.f, 0.f, 0.f, 0.f);
        __syncthreads();
        int base = b * GPC;
        for (int g = tid; g < GPC; g += 512) {
            int4   d4 = ((const int4*)dst)[base + g];
            float4 w4 = ((const float4*)ew)[base + g];
            atomicAdd(&lds[d4.x], w4.x);
            atomicAdd(&lds[d4.y], w4.y);
            atomicAdd(&lds[d4.z], w4.z);
            atomicAdd(&lds[d4.w], w4.w);
        }
        __syncthreads();
        float* dstp = deg_part + b * N_NODES;
        for (int g = tid; g < N_NODES / 4; g += 512)
            ((float4*)dstp)[g] = ((float4*)lds)[g];
    } else if (blk < 144) {
        int b = blk - 128;               // j-chunk [8b, 8b+8)
        if (tid < 256) {
            int j0 = b * 8;
            float uu = 0.f, vv = 0.f;
            #pragma unroll
            for (int jj = 0; jj < 8; ++jj) {
                float w2 = W2[(j0 + jj) * 256 + tid];   // coalesced
                uu = fmaf(W1[j0 + jj], w2, uu);
                vv = fmaf(b1[j0 + jj], w2, vv);
            }
            u_part[b * 256 + tid] = uu;
            v_part[b * 256 + tid] = vv;
        }
    }
    grid.sync();

    // ---- S2: reduce s1 (blk<5), deg (5..9); pqr partials (10..25)
    if (blk < 5) {
        int gid = blk * 512 + tid;
        if (gid < N_NODES / 4) reduce64_f4(s1_part, s1, gid);
    } else if (blk < 10) {
        int gid = (blk - 5) * 512 + tid;
        if (gid < N_NODES / 4) reduce64_f4(deg_part, deg, gid);
    } else if (blk < 26) {
        int c = blk - 10;                // k-chunk [16c, 16c+16)
        if (tid < 16) {
            int kk = c * 16 + tid;
            float uu = 0.f, vv = 0.f;
            #pragma unroll
            for (int b = 0; b < 16; ++b) {
                uu += u_part[b * 256 + kk];
                vv += v_part[b * 256 + kk];
            }
            su[tid] = uu; sv[tid] = vv; sb[tid] = b2[kk];
        }
        __syncthreads();
        float pp = 0.f, qq = 0.f, rr = 0.f;
        #pragma unroll
        for (int kk = 0; kk < 16; ++kk) {
            float w3 = W3[(c * 16 + kk) * 512 + tid];   // coalesced
            pp = fmaf(su[kk], w3, pp);
            qq = fmaf(sv[kk], w3, qq);
            rr = fmaf(sb[kk], w3, rr);
        }
        p_part[c * 512 + tid] = pp;
        q_part[c * 512 + tid] = qq;
        r_part[c * 512 + tid] = rr;
    }
    grid.sync();

    // ---- S3: t2_part (blk<64), B_part (64..127)
    if (blk < 64) {
        chunk_scatter(src, dst, ew, s1, lds, t2_part, blk, tid);
    } else if (blk < 128) {
        chunk_scatter(src, dst, ew, deg, lds, B_part, blk - 64, tid);
    }
    grid.sync();

    // ---- S4: reduce t2 (blk<5), Bf (5..9); pqr final (blk==10)
    if (blk < 5) {
        int gid = blk * 512 + tid;
        if (gid < N_NODES / 4) reduce64_f4(t2_part, t2, gid);
    } else if (blk < 10) {
        int gid = (blk - 5) * 512 + tid;
        if (gid < N_NODES / 4) reduce64_f4(B_part, Bf, gid);
    } else if (blk == 10) {
        float pp = 0.f, qq = 0.f, rr = 0.f;
        #pragma unroll
        for (int c = 0; c < 16; ++c) {
            pp += p_part[c * 512 + tid];
            qq += q_part[c * 512 + tid];
            rr += r_part[c * 512 + tid];
        }
        p[tid] = pp; q[tid] = qq; r[tid] = rr;
    }
    grid.sync();

    // ---- S5: A_part (blk<64)
    if (blk < 64) {
        chunk_scatter(src, dst, ew, t2, lds, A_part, blk, tid);
    }
    grid.sync();

    // ---- S6: output; grid-stride over 313 tiles of 32 nodes.
    // Per tile: fold the 64-way A reduce into the prologue, then write
    // 32 nodes x 128 float4 of sigmoid(a*p + b*q + d*r + b3).
    for (int tile = blk; tile < (N_NODES + 31) / 32; tile += GRID) {
        int n0 = tile * 32;
        int nn = (N_NODES - n0 < 32) ? (N_NODES - n0) : 32;
        __syncthreads();                  // protect sA/A_l reuse across tiles
        {
            int nl = tid >> 4, g = tid & 15;
            float s = 0.f;
            if (nl < nn) {
                int n = n0 + nl;
                s = A_part[g * N_NODES + n] + A_part[(g + 16) * N_NODES + n] +
                    A_part[(g + 32) * N_NODES + n] + A_part[(g + 48) * N_NODES + n];
            }
            sA[tid] = s;
        }
        __syncthreads();
        if (tid < 32 && tid < nn) {
            float s = 0.f;
            #pragma unroll
            for (int g = 0; g < 16; ++g) s += sA[tid * 16 + g];
            A_l[tid] = s;
            B_l[tid] = Bf[n0 + tid];
            D_l[tid] = deg[n0 + tid];
        }
        __syncthreads();
        #pragma unroll
        for (int h = 0; h < 8; ++h) {
            int idx = h * 512 + tid;      // 0..4095 within tile
            int nl = idx >> 7;            // local node 0..31
            int j = idx & 127;            // float4 column
            if (nl < nn) {
                float a = A_l[nl], b = B_l[nl], dg = D_l[nl];
                float4 P = ((const float4*)p)[j];
                float4 Q = ((const float4*)q)[j];
                float4 R = ((const float4*)r)[j];
                float4 B3 = ((const float4*)b3)[j];
                float4 o;
                float zx = fmaf(a, P.x, fmaf(b, Q.x, fmaf(dg, R.x, B3.x)));
                float zy = fmaf(a, P.y, fmaf(b, Q.y, fmaf(dg, R.y, B3.y)));
                float zz = fmaf(a, P.z, fmaf(b, Q.z, fmaf(dg, R.z, B3.z)));
                float zw = fmaf(a, P.w, fmaf(b, Q.w, fmaf(dg, R.w, B3.w)));
                o.x = 1.f / (1.f + __expf(-zx));
                o.y = 1.f / (1.f + __expf(-zy));
                o.z = 1.f / (1.f + __expf(-zz));
                o.w = 1.f / (1.f + __expf(-zw));
                ((float4*)out)[(size_t)(n0 + nl) * 128 + j] = o;
            }
        }
    }
}

extern "C" void kernel_launch(void* const* d_in, const int* in_sizes, int n_in,
                              void* d_out, int out_size, void* d_ws, size_t ws_size,
                              hipStream_t stream) {
    const float* x  = (const float*)d_in[0];
    const int*   ei = (const int*)d_in[1];
    const float* ew = (const float*)d_in[2];
    const float* W1 = (const float*)d_in[3];
    const float* b1 = (const float*)d_in[4];
    const float* W2 = (const float*)d_in[5];
    const float* b2 = (const float*)d_in[6];
    const float* W3 = (const float*)d_in[7];
    const float* b3 = (const float*)d_in[8];
    float* out = (float*)d_out;
    float* ws  = (float*)d_ws;

    const int* src = ei;            // edge_index[0]
    const int* dst = ei + N_EDGES;  // edge_index[1]

    void* args[] = {
        (void*)&src, (void*)&dst, (void*)&ew, (void*)&x,
        (void*)&W1, (void*)&b1, (void*)&W2, (void*)&b2,
        (void*)&W3, (void*)&b3, (void*)&ws, (void*)&out,
    };
    hipLaunchCooperativeKernel((void*)fused_kernel, dim3(GRID), dim3(512),
                               args, 0, stream);
}

// Round 8
// 133.502 us; speedup vs baseline: 1.8064x; 1.8064x over previous
//
#include <hip/hip_runtime.h>
#include <math.h>

#define N_NODES 10000
#define N_EDGES 160000
#define NCHUNK 32                   // edge chunks per scattered quantity
#define EPC (N_EDGES / NCHUNK)      // 5000 edges per chunk
#define GPC (EPC / 4)               // 1250 int4-groups per chunk
#define NF4 (N_NODES / 4)           // 2500 float4 columns per node array

// 4 dispatches, 3 boundaries, no global atomics, no grid.sync (25+ us/sync on
// 8 XCDs -- measured R7). Reduces are folded into consumers: each scatter
// block redundantly tree-reduces the 32 input partials (1.28 MB, sequential,
// L3-resident) into LDS, then gathers from LDS during its scatter.
//
// Workspace layout (floats):
//   [0       .. 10000)    deg  (final)   written by K2 block 32
//   [10000   .. 20000)    Bf   (final)   written by K3 block 33
//   [20000   .. 20512)    p              written by K3 block 32
//   [20512   .. 21024)    q
//   [21024   .. 21536)    r
//   [22000   .. 26096)    u_part[16][256]
//   [26096   .. 30192)    v_part[16][256]
//   [30192   .. 38384)    p_part[16][512]
//   [38384   .. 46576)    q_part[16][512]
//   [46576   .. 54768)    r_part[16][512]
//   [60000   .. 380000)   s1_part[32][10000]
//   [380000  .. 700000)   deg_part[32][10000]
//   [700000  .. 1020000)  t2_part[32][10000]
//   [1020000 .. 1340000)  B_part[32][10000]
//   [1340000 .. 1660000)  A_part[32][10000]
// All arrays written before read; no zeroing dispatch.

// ---------- K1: level-1 LDS scatters + u/v partials ------------------------
// blocks 0..31: s1_part[b] = chunk-scatter(ew * x[src])
// blocks 32..63: deg_part[b] = chunk-scatter(ew)
// blocks 64..79: u/v partial j-chunk (b-64)
__global__ __launch_bounds__(512) void k1_kernel(
        const int* __restrict__ src, const int* __restrict__ dst,
        const float* __restrict__ ew, const float* __restrict__ x,
        float* __restrict__ s1_part, float* __restrict__ deg_part,
        const float* __restrict__ W1, const float* __restrict__ b1,
        const float* __restrict__ W2,
        float* __restrict__ u_part, float* __restrict__ v_part) {
    int tid = threadIdx.x;
    int blk = blockIdx.x;
    if (blk < 64) {
        __shared__ __align__(16) float lds[N_NODES];
        for (int g = tid; g < NF4; g += 512)
            ((float4*)lds)[g] = make_float4(0.f, 0.f, 0.f, 0.f);
        __syncthreads();
        int b = blk & 31;
        bool is_s1 = (blk < 32);
        int base = b * GPC;
        for (int g = tid; g < GPC; g += 512) {
            int4   d4 = ((const int4*)dst)[base + g];
            float4 w4 = ((const float4*)ew)[base + g];
            if (is_s1) {
                int4 s4 = ((const int4*)src)[base + g];
                atomicAdd(&lds[d4.x], w4.x * x[s4.x]);
                atomicAdd(&lds[d4.y], w4.y * x[s4.y]);
                atomicAdd(&lds[d4.z], w4.z * x[s4.z]);
                atomicAdd(&lds[d4.w], w4.w * x[s4.w]);
            } else {
                atomicAdd(&lds[d4.x], w4.x);
                atomicAdd(&lds[d4.y], w4.y);
                atomicAdd(&lds[d4.z], w4.z);
                atomicAdd(&lds[d4.w], w4.w);
            }
        }
        __syncthreads();
        float* dstp = (is_s1 ? s1_part : deg_part) + b * N_NODES;
        for (int g = tid; g < NF4; g += 512)
            ((float4*)dstp)[g] = ((float4*)lds)[g];
    } else {
        int b = blk - 64;                // 0..15, j-chunk [8b, 8b+8)
        if (tid < 256) {
            int j0 = b * 8;
            float uu = 0.f, vv = 0.f;
            #pragma unroll
            for (int jj = 0; jj < 8; ++jj) {
                float w2 = W2[(j0 + jj) * 256 + tid];   // coalesced
                uu = fmaf(W1[j0 + jj], w2, uu);
                vv = fmaf(b1[j0 + jj], w2, vv);
            }
            u_part[b * 256 + tid] = uu;
            v_part[b * 256 + tid] = vv;
        }
    }
}

// Shared helper: reduce 32 partials into lds_src, zero lds_acc, then LDS
// scatter of chunk b gathering from lds_src; write partial out.
__device__ __forceinline__ void fused_reduce_scatter(
        const int* __restrict__ src, const int* __restrict__ dst,
        const float* __restrict__ ew,
        const float* __restrict__ part_in, float* __restrict__ part_out,
        float* lds_src, float* lds_acc, int b, int tid) {
    for (int g = tid; g < NF4; g += 512) {
        float4 a = make_float4(0.f, 0.f, 0.f, 0.f);
        #pragma unroll 8
        for (int c = 0; c < NCHUNK; ++c) {
            float4 v = ((const float4*)(part_in + c * N_NODES))[g];
            a.x += v.x; a.y += v.y; a.z += v.z; a.w += v.w;
        }
        ((float4*)lds_src)[g] = a;
        ((float4*)lds_acc)[g] = make_float4(0.f, 0.f, 0.f, 0.f);
    }
    __syncthreads();
    int base = b * GPC;
    for (int g = tid; g < GPC; g += 512) {
        int4   s4 = ((const int4*)src)[base + g];
        int4   d4 = ((const int4*)dst)[base + g];
        float4 w4 = ((const float4*)ew)[base + g];
        atomicAdd(&lds_acc[d4.x], w4.x * lds_src[s4.x]);
        atomicAdd(&lds_acc[d4.y], w4.y * lds_src[s4.y]);
        atomicAdd(&lds_acc[d4.z], w4.z * lds_src[s4.z]);
        atomicAdd(&lds_acc[d4.w], w4.w * lds_src[s4.w]);
    }
    __syncthreads();
    float* dstp = part_out + b * N_NODES;
    for (int g = tid; g < NF4; g += 512)
        ((float4*)dstp)[g] = ((float4*)lds_acc)[g];
}

// ---------- K2: level-2 fused reduce+scatter + pqr partials ----------------
// blocks 0..31:  t2_part[b]  (input s1_part);
// blocks 32..63: B_part[b]   (input deg_part); block 32 also stores final deg
// blocks 64..79: p/q/r partial k-chunk (blk-64)
__global__ __launch_bounds__(512) void k2_kernel(
        const int* __restrict__ src, const int* __restrict__ dst,
        const float* __restrict__ ew,
        const float* __restrict__ s1_part, const float* __restrict__ deg_part,
        float* __restrict__ t2_part, float* __restrict__ B_part,
        float* __restrict__ deg,
        const float* __restrict__ u_part, const float* __restrict__ v_part,
        const float* __restrict__ b2, const float* __restrict__ W3,
        float* __restrict__ p_part, float* __restrict__ q_part,
        float* __restrict__ r_part) {
    int tid = threadIdx.x;
    int blk = blockIdx.x;
    if (blk < 64) {
        __shared__ __align__(16) float lds_src[N_NODES];
        __shared__ __align__(16) float lds_acc[N_NODES];
        bool is_t2 = (blk < 32);
        int b = blk & 31;
        fused_reduce_scatter(src, dst, ew,
                             is_t2 ? s1_part : deg_part,
                             is_t2 ? t2_part : B_part,
                             lds_src, lds_acc, b, tid);
        if (blk == 32) {  // lds_src holds the fully-reduced deg
            for (int g = tid; g < NF4; g += 512)
                ((float4*)deg)[g] = ((float4*)lds_src)[g];
        }
    } else {
        int c = blk - 64;                // 0..15, k-chunk [16c,16c+16)
        __shared__ float su[16], sv[16], sb[16];
        if (tid < 16) {
            int kk = c * 16 + tid;
            float uu = 0.f, vv = 0.f;
            #pragma unroll
            for (int b = 0; b < 16; ++b) {
                uu += u_part[b * 256 + kk];
                vv += v_part[b * 256 + kk];
            }
            su[tid] = uu; sv[tid] = vv; sb[tid] = b2[kk];
        }
        __syncthreads();
        float pp = 0.f, qq = 0.f, rr = 0.f;
        #pragma unroll
        for (int kk = 0; kk < 16; ++kk) {
            float w3 = W3[(c * 16 + kk) * 512 + tid];   // coalesced
            pp = fmaf(su[kk], w3, pp);
            qq = fmaf(sv[kk], w3, qq);
            rr = fmaf(sb[kk], w3, rr);
        }
        p_part[c * 512 + tid] = pp;
        q_part[c * 512 + tid] = qq;
        r_part[c * 512 + tid] = rr;
    }
}

// ---------- K3: level-3 fused reduce+scatter + pqr final + Bf --------------
// blocks 0..31: A_part[b] (input t2_part); block 32: p/q/r final;
// block 33: Bf = reduce(B_part)
__global__ __launch_bounds__(512) void k3_kernel(
        const int* __restrict__ src, const int* __restrict__ dst,
        const float* __restrict__ ew,
        const float* __restrict__ t2_part, const float* __restrict__ B_part,
        float* __restrict__ A_part, float* __restrict__ Bf,
        const float* __restrict__ p_part, const float* __restrict__ q_part,
        const float* __restrict__ r_part,
        float* __restrict__ p, float* __restrict__ q, float* __restrict__ r) {
    int tid = threadIdx.x;
    int blk = blockIdx.x;
    if (blk < 32) {
        __shared__ __align__(16) float lds_src[N_NODES];
        __shared__ __align__(16) float lds_acc[N_NODES];
        fused_reduce_scatter(src, dst, ew, t2_part, A_part,
                             lds_src, lds_acc, blk, tid);
    } else if (blk == 32) {
        float pp = 0.f, qq = 0.f, rr = 0.f;
        #pragma unroll
        for (int c = 0; c < 16; ++c) {
            pp += p_part[c * 512 + tid];
            qq += q_part[c * 512 + tid];
            rr += r_part[c * 512 + tid];
        }
        p[tid] = pp; q[tid] = qq; r[tid] = rr;
    } else {
        for (int g = tid; g < NF4; g += 512) {
            float4 a = make_float4(0.f, 0.f, 0.f, 0.f);
            #pragma unroll 8
            for (int c = 0; c < NCHUNK; ++c) {
                float4 v = ((const float4*)(B_part + c * N_NODES))[g];
                a.x += v.x; a.y += v.y; a.z += v.z; a.w += v.w;
            }
            ((float4*)Bf)[g] = a;
        }
    }
}

// ---------- K4: output (folds 32-way A-reduce into prologue) ---------------
// 625 blocks x 256 threads; block = 16 nodes x 128 float4 columns.
__global__ __launch_bounds__(256) void output_kernel(
        const float* __restrict__ A_part, const float* __restrict__ Bf,
        const float* __restrict__ deg,
        const float* __restrict__ p, const float* __restrict__ q,
        const float* __restrict__ r, const float* __restrict__ b3,
        float* __restrict__ out) {
    int tid = threadIdx.x;
    int n0 = blockIdx.x * 16;
    __shared__ float sA[256];
    __shared__ float A_l[16], B_l[16], D_l[16];
    {   // 32 partial rows x 16 nodes: thread (c=tid&15, r=tid>>4) sums 2 rows
        int c = tid & 15, rr = tid >> 4;
        sA[tid] = A_part[rr * N_NODES + n0 + c] +
                  A_part[(rr + 16) * N_NODES + n0 + c];
    }
    __syncthreads();
    if (tid < 16) {
        float s = 0.f;
        #pragma unroll
        for (int b = 0; b < 16; ++b) s += sA[b * 16 + tid];
        A_l[tid] = s;
        B_l[tid] = Bf[n0 + tid];
        D_l[tid] = deg[n0 + tid];
    }
    __syncthreads();
    #pragma unroll
    for (int h = 0; h < 8; ++h) {
        int idx = h * 256 + tid;          // 0..2047 within block
        int nl = idx >> 7;                // local node 0..15
        int j = idx & 127;                // float4 column
        float a = A_l[nl], b = B_l[nl], dg = D_l[nl];
        float4 P = ((const float4*)p)[j];
        float4 Q = ((const float4*)q)[j];
        float4 R = ((const float4*)r)[j];
        float4 B3 = ((const float4*)b3)[j];
        float4 o;
        float zx = fmaf(a, P.x, fmaf(b, Q.x, fmaf(dg, R.x, B3.x)));
        float zy = fmaf(a, P.y, fmaf(b, Q.y, fmaf(dg, R.y, B3.y)));
        float zz = fmaf(a, P.z, fmaf(b, Q.z, fmaf(dg, R.z, B3.z)));
        float zw = fmaf(a, P.w, fmaf(b, Q.w, fmaf(dg, R.w, B3.w)));
        o.x = 1.f / (1.f + __expf(-zx));
        o.y = 1.f / (1.f + __expf(-zy));
        o.z = 1.f / (1.f + __expf(-zz));
        o.w = 1.f / (1.f + __expf(-zw));
        ((float4*)out)[(size_t)(n0 + nl) * 128 + j] = o;
    }
}

extern "C" void kernel_launch(void* const* d_in, const int* in_sizes, int n_in,
                              void* d_out, int out_size, void* d_ws, size_t ws_size,
                              hipStream_t stream) {
    const float* x  = (const float*)d_in[0];
    const int*   ei = (const int*)d_in[1];
    const float* ew = (const float*)d_in[2];
    const float* W1 = (const float*)d_in[3];
    const float* b1 = (const float*)d_in[4];
    const float* W2 = (const float*)d_in[5];
    const float* b2 = (const float*)d_in[6];
    const float* W3 = (const float*)d_in[7];
    const float* b3 = (const float*)d_in[8];
    float* out = (float*)d_out;

    float* ws       = (float*)d_ws;
    float* deg      = ws;
    float* Bf       = ws + 10000;
    float* p        = ws + 20000;
    float* q        = ws + 20512;
    float* r        = ws + 21024;
    float* u_part   = ws + 22000;
    float* v_part   = ws + 26096;
    float* p_part   = ws + 30192;
    float* q_part   = ws + 38384;
    float* r_part   = ws + 46576;
    float* s1_part  = ws + 60000;
    float* deg_part = ws + 380000;
    float* t2_part  = ws + 700000;
    float* B_part   = ws + 1020000;
    float* A_part   = ws + 1340000;

    const int* src = ei;            // edge_index[0]
    const int* dst = ei + N_EDGES;  // edge_index[1]

    k1_kernel<<<80, 512, 0, stream>>>(src, dst, ew, x, s1_part, deg_part,
                                      W1, b1, W2, u_part, v_part);
    k2_kernel<<<80, 512, 0, stream>>>(src, dst, ew, s1_part, deg_part,
                                      t2_part, B_part, deg,
                                      u_part, v_part, b2, W3,
                                      p_part, q_part, r_part);
    k3_kernel<<<34, 512, 0, stream>>>(src, dst, ew, t2_part, B_part,
                                      A_part, Bf,
                                      p_part, q_part, r_part, p, q, r);
    output_kernel<<<625, 256, 0, stream>>>(A_part, Bf, deg, p, q, r, b3, out);
}

// Round 9
// 117.510 us; speedup vs baseline: 2.0522x; 1.1361x over previous
//
#include <hip/hip_runtime.h>
#include <math.h>

#define N_NODES 10000
#define N_EDGES 160000
#define NCHUNK 64                   // edge chunks per scattered quantity
#define EPC (N_EDGES / NCHUNK)      // 2500 edges per chunk
#define GPC (EPC / 4)               // 625 int4-groups per chunk
#define NF4 (N_NODES / 4)

// R6 skeleton (6 dispatches, ~1-2us boundaries) with halved kernel work:
//  - dual-quantity scatter blocks: one edge-chunk read feeds BOTH quantities
//    of a level (s1+deg, t2+B) into two 40KB LDS arrays (80KB static: OK,
//    proven in R8)
//  - NCHUNK=64: ~1.2 dependent-load iterations per thread per scatter
//  - s1/deg stored interleaved as float2 so K3 gathers one 8B load per edge
//  - no global atomics, no grid.sync (25us/sync, R7), no redundant reduces
//    (10us/block, R8)
//
// Workspace layout (floats):
//   [0       .. 20000)    sd   (final)  float2(s1,deg) per node   [K2]
//   [20000   .. 30000)    t2   (final)                            [K4]
//   [30000   .. 40000)    Bf   (final)                            [K5]
//   [40000   .. 40512)    p = (W1row@W2)@W3                       [K5]
//   [40512   .. 41024)    q = (b1@W2)@W3                          [K5]
//   [41024   .. 41536)    r = b2@W3                               [K5]
//   [42000   .. 46096)    u_part[16][256]                         [K1]
//   [46096   .. 50192)    v_part[16][256]                         [K1]
//   [50192   .. 58384)    p_part[16][512]                         [K2]
//   [58384   .. 66576)    q_part[16][512]                         [K2]
//   [66576   .. 74768)    r_part[16][512]                         [K2]
//   [80000   .. 720000)   s1_part[64][10000]                      [K1]
//   [720000  .. 1360000)  deg_part[64][10000]                     [K1]
//   [1360000 .. 2000000)  t2_part[64][10000]                      [K3]
//   [2000000 .. 2640000)  B_part[64][10000]                       [K3]
//   [2640000 .. 3280000)  A_part[64][10000]                       [K5]
// All arrays written before read; no zeroing dispatch.

// ---------- K1: dual s1+deg chunk scatter + u/v partials -------------------
// blocks 0..63: chunk b -> s1_part[b], deg_part[b]
// blocks 64..79: u/v partial j-chunk (b-64)
__global__ __launch_bounds__(512) void k1_kernel(
        const int* __restrict__ src, const int* __restrict__ dst,
        const float* __restrict__ ew, const float* __restrict__ x,
        float* __restrict__ s1_part, float* __restrict__ deg_part,
        const float* __restrict__ W1, const float* __restrict__ b1,
        const float* __restrict__ W2,
        float* __restrict__ u_part, float* __restrict__ v_part) {
    int tid = threadIdx.x;
    int blk = blockIdx.x;
    if (blk < 64) {
        __shared__ __align__(16) float lds_s1[N_NODES];
        __shared__ __align__(16) float lds_dg[N_NODES];
        for (int g = tid; g < NF4; g += 512) {
            ((float4*)lds_s1)[g] = make_float4(0.f, 0.f, 0.f, 0.f);
            ((float4*)lds_dg)[g] = make_float4(0.f, 0.f, 0.f, 0.f);
        }
        __syncthreads();
        int base = blk * GPC;
        for (int g = tid; g < GPC; g += 512) {
            int4   s4 = ((const int4*)src)[base + g];
            int4   d4 = ((const int4*)dst)[base + g];
            float4 w4 = ((const float4*)ew)[base + g];
            atomicAdd(&lds_s1[d4.x], w4.x * x[s4.x]);
            atomicAdd(&lds_dg[d4.x], w4.x);
            atomicAdd(&lds_s1[d4.y], w4.y * x[s4.y]);
            atomicAdd(&lds_dg[d4.y], w4.y);
            atomicAdd(&lds_s1[d4.z], w4.z * x[s4.z]);
            atomicAdd(&lds_dg[d4.z], w4.z);
            atomicAdd(&lds_s1[d4.w], w4.w * x[s4.w]);
            atomicAdd(&lds_dg[d4.w], w4.w);
        }
        __syncthreads();
        float* p1 = s1_part + blk * N_NODES;
        float* p2 = deg_part + blk * N_NODES;
        for (int g = tid; g < NF4; g += 512) {
            ((float4*)p1)[g] = ((float4*)lds_s1)[g];
            ((float4*)p2)[g] = ((float4*)lds_dg)[g];
        }
    } else {
        int b = blk - 64;                // 0..15, j-chunk [8b, 8b+8)
        if (tid < 256) {
            int j0 = b * 8;
            float uu = 0.f, vv = 0.f;
            #pragma unroll
            for (int jj = 0; jj < 8; ++jj) {
                float w2 = W2[(j0 + jj) * 256 + tid];   // coalesced
                uu = fmaf(W1[j0 + jj], w2, uu);
                vv = fmaf(b1[j0 + jj], w2, vv);
            }
            u_part[b * 256 + tid] = uu;
            v_part[b * 256 + tid] = vv;
        }
    }
}

// ---------- K2: reduce s1+deg -> interleaved sd; pqr partials --------------
// blocks 0..19: node n = blk*512+tid; sd[n] = (sum s1_part, sum deg_part)
// blocks 20..35: p/q/r partial k-chunk (blk-20)
__global__ __launch_bounds__(512) void k2_kernel(
        const float* __restrict__ s1_part, const float* __restrict__ deg_part,
        float* __restrict__ sd,
        const float* __restrict__ u_part, const float* __restrict__ v_part,
        const float* __restrict__ b2, const float* __restrict__ W3,
        float* __restrict__ p_part, float* __restrict__ q_part,
        float* __restrict__ r_part) {
    int tid = threadIdx.x;
    int blk = blockIdx.x;
    if (blk < 20) {
        int n = blk * 512 + tid;
        if (n < N_NODES) {
            float s = 0.f, d = 0.f;
            #pragma unroll 8
            for (int c = 0; c < NCHUNK; ++c) {
                s += s1_part[c * N_NODES + n];   // coalesced across tid
                d += deg_part[c * N_NODES + n];
            }
            ((float2*)sd)[n] = make_float2(s, d);
        }
    } else {
        int c = blk - 20;                // 0..15, k-chunk [16c,16c+16)
        __shared__ float su[16], sv[16], sb[16];
        if (tid < 16) {
            int kk = c * 16 + tid;
            float uu = 0.f, vv = 0.f;
            #pragma unroll
            for (int b = 0; b < 16; ++b) {
                uu += u_part[b * 256 + kk];
                vv += v_part[b * 256 + kk];
            }
            su[tid] = uu; sv[tid] = vv; sb[tid] = b2[kk];
        }
        __syncthreads();
        float pp = 0.f, qq = 0.f, rr = 0.f;
        #pragma unroll
        for (int kk = 0; kk < 16; ++kk) {
            float w3 = W3[(c * 16 + kk) * 512 + tid];   // coalesced
            pp = fmaf(su[kk], w3, pp);
            qq = fmaf(sv[kk], w3, qq);
            rr = fmaf(sb[kk], w3, rr);
        }
        p_part[c * 512 + tid] = pp;
        q_part[c * 512 + tid] = qq;
        r_part[c * 512 + tid] = rr;
    }
}

// ---------- K3: dual t2+B chunk scatter (one float2 gather per edge) -------
// blocks 0..63: chunk b -> t2_part[b], B_part[b]
__global__ __launch_bounds__(512) void k3_kernel(
        const int* __restrict__ src, const int* __restrict__ dst,
        const float* __restrict__ ew, const float* __restrict__ sd,
        float* __restrict__ t2_part, float* __restrict__ B_part) {
    int tid = threadIdx.x;
    int blk = blockIdx.x;
    __shared__ __align__(16) float lds_t2[N_NODES];
    __shared__ __align__(16) float lds_B[N_NODES];
    for (int g = tid; g < NF4; g += 512) {
        ((float4*)lds_t2)[g] = make_float4(0.f, 0.f, 0.f, 0.f);
        ((float4*)lds_B)[g]  = make_float4(0.f, 0.f, 0.f, 0.f);
    }
    __syncthreads();
    const float2* sdv = (const float2*)sd;
    int base = blk * GPC;
    for (int g = tid; g < GPC; g += 512) {
        int4   s4 = ((const int4*)src)[base + g];
        int4   d4 = ((const int4*)dst)[base + g];
        float4 w4 = ((const float4*)ew)[base + g];
        float2 vx = sdv[s4.x], vy = sdv[s4.y], vz = sdv[s4.z], vw = sdv[s4.w];
        atomicAdd(&lds_t2[d4.x], w4.x * vx.x);
        atomicAdd(&lds_B[d4.x],  w4.x * vx.y);
        atomicAdd(&lds_t2[d4.y], w4.y * vy.x);
        atomicAdd(&lds_B[d4.y],  w4.y * vy.y);
        atomicAdd(&lds_t2[d4.z], w4.z * vz.x);
        atomicAdd(&lds_B[d4.z],  w4.z * vz.y);
        atomicAdd(&lds_t2[d4.w], w4.w * vw.x);
        atomicAdd(&lds_B[d4.w],  w4.w * vw.y);
    }
    __syncthreads();
    float* p1 = t2_part + blk * N_NODES;
    float* p2 = B_part + blk * N_NODES;
    for (int g = tid; g < NF4; g += 512) {
        ((float4*)p1)[g] = ((float4*)lds_t2)[g];
        ((float4*)p2)[g] = ((float4*)lds_B)[g];
    }
}

// ---------- K4: reduce t2 --------------------------------------------------
__global__ __launch_bounds__(512) void k4_kernel(
        const float* __restrict__ t2_part, float* __restrict__ t2) {
    int n = blockIdx.x * 512 + threadIdx.x;
    if (n < N_NODES) {
        float s = 0.f;
        #pragma unroll 8
        for (int c = 0; c < NCHUNK; ++c) s += t2_part[c * N_NODES + n];
        t2[n] = s;
    }
}

// ---------- K5: A-scatter + Bf reduce + pqr final --------------------------
// blocks 0..63: A_part[b] = chunk-scatter(ew * t2[src])
// blocks 64..83: Bf reduce; block 84: p/q/r final
__global__ __launch_bounds__(512) void k5_kernel(
        const int* __restrict__ src, const int* __restrict__ dst,
        const float* __restrict__ ew, const float* __restrict__ t2,
        float* __restrict__ A_part,
        const float* __restrict__ B_part, float* __restrict__ Bf,
        const float* __restrict__ p_part, const float* __restrict__ q_part,
        const float* __restrict__ r_part,
        float* __restrict__ p, float* __restrict__ q, float* __restrict__ r) {
    int tid = threadIdx.x;
    int blk = blockIdx.x;
    if (blk < 64) {
        __shared__ __align__(16) float lds[N_NODES];
        for (int g = tid; g < NF4; g += 512)
            ((float4*)lds)[g] = make_float4(0.f, 0.f, 0.f, 0.f);
        __syncthreads();
        int base = blk * GPC;
        for (int g = tid; g < GPC; g += 512) {
            int4   s4 = ((const int4*)src)[base + g];
            int4   d4 = ((const int4*)dst)[base + g];
            float4 w4 = ((const float4*)ew)[base + g];
            atomicAdd(&lds[d4.x], w4.x * t2[s4.x]);
            atomicAdd(&lds[d4.y], w4.y * t2[s4.y]);
            atomicAdd(&lds[d4.z], w4.z * t2[s4.z]);
            atomicAdd(&lds[d4.w], w4.w * t2[s4.w]);
        }
        __syncthreads();
        float* dstp = A_part + blk * N_NODES;
        for (int g = tid; g < NF4; g += 512)
            ((float4*)dstp)[g] = ((float4*)lds)[g];
    } else if (blk < 84) {
        int n = (blk - 64) * 512 + tid;
        if (n < N_NODES) {
            float s = 0.f;
            #pragma unroll 8
            for (int c = 0; c < NCHUNK; ++c) s += B_part[c * N_NODES + n];
            Bf[n] = s;
        }
    } else {
        float pp = 0.f, qq = 0.f, rr = 0.f;
        #pragma unroll
        for (int c = 0; c < 16; ++c) {
            pp += p_part[c * 512 + tid];
            qq += q_part[c * 512 + tid];
            rr += r_part[c * 512 + tid];
        }
        p[tid] = pp; q[tid] = qq; r[tid] = rr;
    }
}

// ---------- K6: output (folds 64-way A-reduce into prologue) ---------------
// 625 blocks x 256 threads; block = 16 nodes x 128 float4 columns.
__global__ __launch_bounds__(256) void output_kernel(
        const float* __restrict__ A_part, const float* __restrict__ Bf,
        const float* __restrict__ sd,
        const float* __restrict__ p, const float* __restrict__ q,
        const float* __restrict__ r, const float* __restrict__ b3,
        float* __restrict__ out) {
    int tid = threadIdx.x;
    int n0 = blockIdx.x * 16;
    __shared__ float sA[256];
    __shared__ float A_l[16], B_l[16], D_l[16];
    {   // 64 partial rows x 16 nodes: thread (c=tid&15, r=tid>>4) sums 4 rows
        int c = tid & 15, rr = tid >> 4;
        int n = n0 + c;
        sA[tid] = A_part[rr * N_NODES + n] + A_part[(rr + 16) * N_NODES + n] +
                  A_part[(rr + 32) * N_NODES + n] + A_part[(rr + 48) * N_NODES + n];
    }
    __syncthreads();
    if (tid < 16) {
        float s = 0.f;
        #pragma unroll
        for (int b = 0; b < 16; ++b) s += sA[b * 16 + tid];
        A_l[tid] = s;
        B_l[tid] = Bf[n0 + tid];
        D_l[tid] = ((const float2*)sd)[n0 + tid].y;   // deg
    }
    __syncthreads();
    #pragma unroll
    for (int h = 0; h < 8; ++h) {
        int idx = h * 256 + tid;          // 0..2047 within block
        int nl = idx >> 7;                // local node 0..15
        int j = idx & 127;                // float4 column
        float a = A_l[nl], b = B_l[nl], dg = D_l[nl];
        float4 P = ((const float4*)p)[j];
        float4 Q = ((const float4*)q)[j];
        float4 R = ((const float4*)r)[j];
        float4 B3 = ((const float4*)b3)[j];
        float4 o;
        float zx = fmaf(a, P.x, fmaf(b, Q.x, fmaf(dg, R.x, B3.x)));
        float zy = fmaf(a, P.y, fmaf(b, Q.y, fmaf(dg, R.y, B3.y)));
        float zz = fmaf(a, P.z, fmaf(b, Q.z, fmaf(dg, R.z, B3.z)));
        float zw = fmaf(a, P.w, fmaf(b, Q.w, fmaf(dg, R.w, B3.w)));
        o.x = 1.f / (1.f + __expf(-zx));
        o.y = 1.f / (1.f + __expf(-zy));
        o.z = 1.f / (1.f + __expf(-zz));
        o.w = 1.f / (1.f + __expf(-zw));
        ((float4*)out)[(size_t)(n0 + nl) * 128 + j] = o;
    }
}

extern "C" void kernel_launch(void* const* d_in, const int* in_sizes, int n_in,
                              void* d_out, int out_size, void* d_ws, size_t ws_size,
                              hipStream_t stream) {
    const float* x  = (const float*)d_in[0];
    const int*   ei = (const int*)d_in[1];
    const float* ew = (const float*)d_in[2];
    const float* W1 = (const float*)d_in[3];
    const float* b1 = (const float*)d_in[4];
    const float* W2 = (const float*)d_in[5];
    const float* b2 = (const float*)d_in[6];
    const float* W3 = (const float*)d_in[7];
    const float* b3 = (const float*)d_in[8];
    float* out = (float*)d_out;

    float* ws       = (float*)d_ws;
    float* sd       = ws;              // float2(s1,deg) x 10000
    float* t2       = ws + 20000;
    float* Bf       = ws + 30000;
    float* p        = ws + 40000;
    float* q        = ws + 40512;
    float* r        = ws + 41024;
    float* u_part   = ws + 42000;
    float* v_part   = ws + 46096;
    float* p_part   = ws + 50192;
    float* q_part   = ws + 58384;
    float* r_part   = ws + 66576;
    float* s1_part  = ws + 80000;
    float* deg_part = ws + 720000;
    float* t2_part  = ws + 1360000;
    float* B_part   = ws + 2000000;
    float* A_part   = ws + 2640000;

    const int* src = ei;            // edge_index[0]
    const int* dst = ei + N_EDGES;  // edge_index[1]

    k1_kernel<<<80, 512, 0, stream>>>(src, dst, ew, x, s1_part, deg_part,
                                      W1, b1, W2, u_part, v_part);
    k2_kernel<<<36, 512, 0, stream>>>(s1_part, deg_part, sd,
                                      u_part, v_part, b2, W3,
                                      p_part, q_part, r_part);
    k3_kernel<<<64, 512, 0, stream>>>(src, dst, ew, sd, t2_part, B_part);
    k4_kernel<<<20, 512, 0, stream>>>(t2_part, t2);
    k5_kernel<<<85, 512, 0, stream>>>(src, dst, ew, t2, A_part,
                                      B_part, Bf,
                                      p_part, q_part, r_part, p, q, r);
    output_kernel<<<625, 256, 0, stream>>>(A_part, Bf, sd, p, q, r, b3, out);
}